// Round 6
// baseline (19.463 us; speedup 1.0000x reference)
//
#include <hip/hip_runtime.h>
#include <hip/hip_bf16.h>

#define SEQ 4096
#define DIM 1024

typedef __attribute__((ext_vector_type(8))) short short8;
typedef __attribute__((ext_vector_type(4))) float f32x4;
typedef __attribute__((ext_vector_type(4))) unsigned short us4;

__device__ __forceinline__ us4 cvt4(float a, float b, float c, float d) {
    union { us4 v; __hip_bfloat162 h[2]; } u;
    u.h[0] = __float22bfloat162_rn(make_float2(a, b));
    u.h[1] = __float22bfloat162_rn(make_float2(c, d));
    return u.v;
}
__device__ __forceinline__ short8 cvt8(float4 a, float4 b) {
    union { short8 s; __hip_bfloat162 h[4]; } u;
    u.h[0] = __float22bfloat162_rn(make_float2(a.x, a.y));
    u.h[1] = __float22bfloat162_rn(make_float2(a.z, a.w));
    u.h[2] = __float22bfloat162_rn(make_float2(b.x, b.y));
    u.h[3] = __float22bfloat162_rn(make_float2(b.z, b.w));
    return u.s;
}

// Single fused kernel. Grid = 64 blocks (one 16-col tile each) x 512 thr.
// LDS sA holds all 64 bf16 mean rows in MFMA A-fragment layout,
// 16B units indexed (rt*32+ks)*64 + (slot ^ (ks&15))  [XOR bank swizzle].
__global__ __launch_bounds__(512) void k_fused(
    const float* __restrict__ latent,   // [8][SEQ][DIM]
    const int*   __restrict__ mask,     // [8][SEQ]
    const float* __restrict__ Wm,       // [DIM][DIM] row-major
    const float* __restrict__ bias,     // [DIM]
    float*       __restrict__ out)      // [64][DIM]
{
    __shared__ unsigned short sA[64 * 1024];   // 128 KB
    __shared__ int s_pos[8][8];

    const int ct   = blockIdx.x;       // col tile: cols ct*16..+15
    const int tid  = threadIdx.x;
    const int lane = tid & 63;
    const int wid  = tid >> 6;         // 0..7

    // ---- Phase A: wave w scans batch w's mask (early-exit) ----
    {
        const int b = wid;
        if (lane < 8) s_pos[wid][lane] = SEQ;
        int carry = 0;
        for (int ch = 0; ch < SEQ / 256 && carry < 8; ++ch) {
            const int4 m = *(const int4*)(mask + (size_t)b * SEQ + ch * 256 + lane * 4);
            const int cnt = m.x + m.y + m.z + m.w;
            int v = cnt;
            #pragma unroll
            for (int off = 1; off < 64; off <<= 1) {
                int o = __shfl_up(v, off, 64);
                if (lane >= off) v += o;
            }
            const int excl = carry + v - cnt;
            if (excl < 8 && cnt > 0) {
                int vals[4] = {m.x, m.y, m.z, m.w};
                int rank = excl;
                #pragma unroll
                for (int i = 0; i < 4; ++i) {
                    if (vals[i]) {
                        if (rank < 8) s_pos[wid][rank] = ch * 256 + lane * 4 + i;
                        ++rank;
                    }
                }
            }
            carry += __shfl(v, 63, 64);
        }
    }
    // wave-local dependency only (own s_pos rows) — but waves also read their
    // own slice; a cheap barrier keeps it simple and correct:
    __syncthreads();

    // ---- Phase B: wave w -> 8 bucket means of batch w -> bf16 LDS frags ----
    {
        const int b = wid;
        const float4* lb = (const float4*)(latent + (size_t)b * SEQ * DIM);
        #pragma unroll 1
        for (int p = 0; p < 8; ++p) {
            const int start = (p == 0) ? 0 : s_pos[b][p - 1] + 1;
            const int endi  = min(s_pos[b][p], SEQ - 1);
            float4 acc[4] = {};
            for (int r = start; r <= endi; ++r) {     // coalesced 1KB/instr
                const float4* rp = lb + (size_t)r * (DIM / 4);
                #pragma unroll
                for (int q = 0; q < 4; ++q) {
                    float4 v = rp[q * 64 + lane];
                    acc[q].x += v.x; acc[q].y += v.y;
                    acc[q].z += v.z; acc[q].w += v.w;
                }
            }
            const float inv = (endi >= start) ? 1.0f / (float)(endi - start + 1) : 0.0f;
            const int r   = b * 8 + p;                // output row
            const int rt  = r >> 4, l15 = r & 15;
            #pragma unroll
            for (int q = 0; q < 4; ++q) {
                // lane covers k = q*256 + lane*4 .. +3
                const int ks   = q * 8 + (lane >> 3);
                const int lk   = (lane >> 1) & 3;
                const int slot = (lk * 16 + l15) ^ (ks & 15);
                unsigned short* dst =
                    &sA[(((size_t)(rt * 32 + ks) * 64 + slot) * 8) + (lane & 1) * 4];
                *(us4*)dst = cvt4(acc[q].x * inv, acc[q].y * inv,
                                  acc[q].z * inv, acc[q].w * inv);
            }
        }
    }
    __syncthreads();

    // ---- Phase C: MFMA GEMM. wave = (rt = wid&3, kh = wid>>2) ----
    const int rt  = wid & 3;
    const int kh  = wid >> 2;
    const int l15 = lane & 15;
    const int lk  = lane >> 4;
    const int col = ct * 16 + l15;
    const float* wrow = Wm + (size_t)col * DIM;

    f32x4 acc = {0.f, 0.f, 0.f, 0.f};
    #pragma unroll
    for (int s = 0; s < 16; ++s) {
        const int ks = kh * 16 + s;
        const int sl = lane ^ (ks & 15);
        short8 a = *(const short8*)&sA[((size_t)(rt * 32 + ks) * 64 + sl) * 8];
        const float4 w0 = *(const float4*)(wrow + ks * 32 + lk * 8);
        const float4 w1 = *(const float4*)(wrow + ks * 32 + lk * 8 + 4);
        short8 bf = cvt8(w0, w1);
        acc = __builtin_amdgcn_mfma_f32_16x16x32_bf16(a, bf, acc, 0, 0, 0);
    }

    // ---- kh-pair reduce (fixed order) + bias + store ----
    __syncthreads();                       // all sA reads done; safe to alias
    f32x4* sred = (f32x4*)sA;              // 4 KB alias
    if (kh == 1) sred[rt * 64 + lane] = acc;
    __syncthreads();
    if (kh == 0) {
        f32x4 o = sred[rt * 64 + lane];
        acc = acc + o;
        const float bv = bias[col];
        #pragma unroll
        for (int j = 0; j < 4; ++j)        // D: row=(lane>>4)*4+j, col=lane&15
            out[(size_t)(rt * 16 + lk * 4 + j) * DIM + col] = acc[j] + bv;
    }
}

extern "C" void kernel_launch(void* const* d_in, const int* in_sizes, int n_in,
                              void* d_out, int out_size, void* d_ws, size_t ws_size,
                              hipStream_t stream) {
    const float* latent = (const float*)d_in[0];   // (8,4096,1024) f32
    const int*   mask   = (const int*)d_in[1];     // (8,4096,1) int32
    const float* Wm     = (const float*)d_in[2];   // (1024,1024) f32
    const float* bias   = (const float*)d_in[3];   // (1024,) f32
    float* out = (float*)d_out;                    // (8,8,1024) f32

    k_fused<<<64, 512, 0, stream>>>(latent, mask, Wm, bias, out);
}